// Round 13
// baseline (447.787 us; speedup 1.0000x reference)
//
#include <hip/hip_runtime.h>
#include <stdint.h>

// UnarySqrt scan, T=64 steps, N=2^20 channels, exact {0,1} floats.
//   per step: p = x*(1-tr); out = tr + p; tr' = p
//
// R1..R12: five structures, occupancy 8..32 waves/CU, register/asm/LDS-DMA
// pipelines -- ALL plateau at ~2.2-2.4 TB/s. The shared invariant: every
// wave's address stream jumps 4 MB (row stride) between accesses in 1-4 KB
// granules -> HBM sees ~1 KB scatter over 256 MB -> DRAM activate-rate bound
// (~1/3 peak = the observed 2.4). The fast references (harness fill 6.5 TB/s,
// m13 copy 6.29 TB/s) both present LINEAR instantaneous windows.
//
// Fix: identical per-thread recurrence, but grid = 256 blocks x 1024 threads
// (1 block/CU). Each block owns a contiguous 16 KB slice of every row; its
// 16 waves jointly issue one contiguous 16 KB burst per row, and the 256
// near-lockstep blocks sweep each 4 MB row linearly -> two clean streaming
// passes (read in, write out), DRAM-page friendly. Trace in registers; no
// LDS, no barriers. NT stores keep writes from evicting the L3-resident
// input (FETCH_SIZE has shown ~50% L3 hit on reads).

typedef float v4f __attribute__((ext_vector_type(4)));

__global__ __launch_bounds__(1024) void UnarySqrt_kernel(
    const v4f* __restrict__ in,      // [64, stride]
    const v4f* __restrict__ trace0,  // [stride]
    v4f* __restrict__ out,           // [64, stride]
    int stride)                       // N/4
{
    const int idx = blockIdx.x * blockDim.x + threadIdx.x;
    if (idx >= stride) return;

    v4f tr = trace0[idx];
    v4f x  = in[idx];  // prefetch row 0

    #pragma unroll 8
    for (int t = 0; t < 64; ++t) {
        v4f xn;
        if (t + 1 < 64) {
            xn = in[(size_t)(t + 1) * (size_t)stride + (size_t)idx];
        }
        v4f p = x * (1.0f - tr);
        v4f o = tr + p;
        __builtin_nontemporal_store(
            o, &out[(size_t)t * (size_t)stride + (size_t)idx]);
        tr = p;
        x = xn;
    }
}

// Generic fallback (correct for any T, N%4==0).
__global__ __launch_bounds__(256) void UnarySqrt_generic(
    const v4f* __restrict__ in, const v4f* __restrict__ trace0,
    v4f* __restrict__ out, int stride, int T)
{
    int idx = blockIdx.x * blockDim.x + threadIdx.x;
    if (idx >= stride) return;
    v4f tr = trace0[idx];
    for (int t = 0; t < T; ++t) {
        v4f x = in[(size_t)t * stride + idx];
        v4f p = x * (1.0f - tr);
        out[(size_t)t * stride + idx] = tr + p;
        tr = p;
    }
}

extern "C" void kernel_launch(void* const* d_in, const int* in_sizes, int n_in,
                              void* d_out, int out_size, void* d_ws, size_t ws_size,
                              hipStream_t stream) {
    const float* bits   = (const float*)d_in[0];  // [T, N]
    const float* trace0 = (const float*)d_in[1];  // [N]

    int N = in_sizes[1];
    int T = in_sizes[0] / N;
    int stride = N / 4;

    if (T == 64 && (stride % 1024) == 0) {
        // 1024-thread blocks; grid = stride/1024 = 256 at N=2^20 -> 1 block/CU,
        // near-lockstep linear row sweeps.
        int grid = stride / 1024;
        UnarySqrt_kernel<<<grid, 1024, 0, stream>>>(
            (const v4f*)bits, (const v4f*)trace0, (v4f*)d_out, stride);
    } else {
        int block = 256;
        int grid = (stride + block - 1) / block;
        UnarySqrt_generic<<<grid, block, 0, stream>>>(
            (const v4f*)bits, (const v4f*)trace0, (v4f*)d_out, stride, T);
    }
}